// Round 4
// baseline (658.226 us; speedup 1.0000x reference)
//
#include <hip/hip_runtime.h>
#include <stdint.h>
#include <stddef.h>

// Problem constants
#define BROWS 8192
#define FEATK 7680
#define HIDN  512

typedef __attribute__((ext_vector_type(8))) __bf16 bf16x8;
typedef __attribute__((ext_vector_type(4))) float f32x4;

// fp32 -> bf16 round-to-nearest-even (bit manip; inputs finite)
__device__ __forceinline__ unsigned short f2b(float f) {
  unsigned int u = __float_as_uint(f);
  unsigned int r = (u + 0x7FFFu + ((u >> 16) & 1u)) >> 16;
  return (unsigned short)r;
}

// ---------------- K0: fp32 -> bf16 conversion (weights only) ----------------
__global__ void cvt_kernel(const float* __restrict__ src, unsigned short* __restrict__ dst, int n4) {
  int i = blockIdx.x * blockDim.x + threadIdx.x;
  int stride = gridDim.x * blockDim.x;
  for (; i < n4; i += stride) {
    float4 v = ((const float4*)src)[i];
    ushort4 o;
    o.x = f2b(v.x); o.y = f2b(v.y); o.z = f2b(v.z); o.w = f2b(v.w);
    ((ushort4*)dst)[i] = o;
  }
}

// ---------------- K1: fused fp32-A GEMM, split-K, register-pipelined ----------------
// P[s] = A(fp32)[64-row stripe] @ W1B(bf16)^T over k-chunk s. BM=64, BN=512, BK=32.
// 256 threads = 4 waves; wave w computes 64 rows x cols [w*128, +128) as 4x8 tiles.
// Tile k+1 staged through VGPRs while tile k computes (register double-buffer):
// global latency hides behind ds_read+MFMA instead of draining at the barrier.
// LDS rows padded to 40 shorts (80 B) -> conflict-free b128 frag reads.
#define K1_BM  64
#define K1_BK  32
#define K1_PAD 40

__global__ __launch_bounds__(256, 2) void gemm1_fused_splitk(
    const float* __restrict__ A,            // [8192, 7680] fp32
    const unsigned short* __restrict__ Bm,  // [512, 7680] bf16
    float* __restrict__ P,                  // [S, 8192, 512] fp32 partials
    int M, int N, int K, int klen) {
  __shared__ unsigned short As[K1_BM * K1_PAD];   // 5 KB
  __shared__ unsigned short Bs[HIDN * K1_PAD];    // 40 KB

  const int tid  = threadIdx.x;
  const int lane = tid & 63;
  const int wid  = tid >> 6;
  const int l16  = lane & 15;
  const int quad = lane >> 4;

  const int rowBase = blockIdx.y * K1_BM;
  const int k_begin = blockIdx.x * klen;
  const int niter   = klen / K1_BK;

  f32x4 acc[4][8] = {};

  // per-thread staging coordinates (constant across iters)
  // A: 2 x float4; chunk c = it*256+tid, row = c>>3 (8 float4/row), kq = c&7
  // B: 8 x uint4 (16B = 8 bf16); chunk c = it*256+tid, row = c>>2 (4/row), ch = c&3
  float4 aA[2];
  uint4  bB[8];

#define K1_GLOAD(k0)                                                              \
  {                                                                               \
    _Pragma("unroll")                                                             \
    for (int it = 0; it < 2; ++it) {                                              \
      int c = it * 256 + tid; int row = c >> 3; int kq = c & 7;                   \
      aA[it] = *(const float4*)(A + (size_t)(rowBase + row) * K + (k0) + kq * 4); \
    }                                                                             \
    _Pragma("unroll")                                                             \
    for (int it = 0; it < 8; ++it) {                                              \
      int c = it * 256 + tid; int row = c >> 2; int ch = c & 3;                   \
      bB[it] = *(const uint4*)(Bm + (size_t)row * K + (k0) + ch * 8);             \
    }                                                                             \
  }

#define K1_STORE_LDS()                                                            \
  {                                                                               \
    _Pragma("unroll")                                                             \
    for (int it = 0; it < 2; ++it) {                                              \
      int c = it * 256 + tid; int row = c >> 3; int kq = c & 7;                   \
      ushort4 o;                                                                  \
      o.x = f2b(aA[it].x); o.y = f2b(aA[it].y);                                   \
      o.z = f2b(aA[it].z); o.w = f2b(aA[it].w);                                   \
      *(ushort4*)(As + row * K1_PAD + kq * 4) = o;                                \
    }                                                                             \
    _Pragma("unroll")                                                             \
    for (int it = 0; it < 8; ++it) {                                              \
      int c = it * 256 + tid; int row = c >> 2; int ch = c & 3;                   \
      *(uint4*)(Bs + row * K1_PAD + ch * 8) = bB[it];                             \
    }                                                                             \
  }

  K1_GLOAD(k_begin)
  K1_STORE_LDS()
  __syncthreads();

  for (int i = 1; i <= niter; ++i) {
    const bool more = (i < niter);
    if (more) K1_GLOAD(k_begin + i * K1_BK)   // issue next tile's loads early

    // compute tile i-1 from LDS
    bf16x8 af[4], bfr[8];
#pragma unroll
    for (int mt = 0; mt < 4; ++mt)
      af[mt] = *(const bf16x8*)(As + (mt * 16 + l16) * K1_PAD + quad * 8);
#pragma unroll
    for (int nt = 0; nt < 8; ++nt)
      bfr[nt] = *(const bf16x8*)(Bs + (wid * 128 + nt * 16 + l16) * K1_PAD + quad * 8);
#pragma unroll
    for (int mt = 0; mt < 4; ++mt)
#pragma unroll
      for (int nt = 0; nt < 8; ++nt)
        acc[mt][nt] = __builtin_amdgcn_mfma_f32_16x16x32_bf16(af[mt], bfr[nt], acc[mt][nt], 0, 0, 0);

    __syncthreads();                 // all waves done reading LDS
    if (more) { K1_STORE_LDS() }     // vmcnt wait lands here, after compute issued
    __syncthreads();                 // writes visible before next compute
  }

  // epilogue: fp32 partials
  float* outp = P + (size_t)blockIdx.x * M * N;
#pragma unroll
  for (int mt = 0; mt < 4; ++mt) {
#pragma unroll
    for (int r = 0; r < 4; ++r) {
      int row = rowBase + mt * 16 + quad * 4 + r;
      float* cp = outp + (size_t)row * N + wid * 128 + l16;
#pragma unroll
      for (int nt = 0; nt < 8; ++nt) cp[nt * 16] = acc[mt][nt][r];
    }
  }
#undef K1_GLOAD
#undef K1_STORE_LDS
}

// Reduce S=4 partials + bias + ReLU -> bf16
__global__ __launch_bounds__(256) void reduce4_bias_relu(
    const float* __restrict__ P, const float* __restrict__ bias,
    unsigned short* __restrict__ H, int MN4, int N4) {
  int i = blockIdx.x * blockDim.x + threadIdx.x;
  if (i >= MN4) return;
  const float4* p = (const float4*)P;
  float4 a = p[i];
  float4 b = p[i + MN4];
  float4 c = p[i + 2 * MN4];
  float4 d = p[i + 3 * MN4];
  float4 bs = ((const float4*)bias)[i % N4];
  ushort4 o;
  o.x = f2b(fmaxf(a.x + b.x + c.x + d.x + bs.x, 0.0f));
  o.y = f2b(fmaxf(a.y + b.y + c.y + d.y + bs.y, 0.0f));
  o.z = f2b(fmaxf(a.z + b.z + c.z + d.z + bs.z, 0.0f));
  o.w = f2b(fmaxf(a.w + b.w + c.w + d.w + bs.w, 0.0f));
  ((ushort4*)H)[i] = o;
}

// ---------------- K2: bf16 GEMM  C = relu(A @ B^T + bias) (m97 structure) ----------------
#define BM 128
#define BN 128
#define BK 64

__global__ __launch_bounds__(256, 2) void gemm_bt_bias_relu(
    const unsigned short* __restrict__ A,
    const unsigned short* __restrict__ Bm,
    const float* __restrict__ bias,
    unsigned short* __restrict__ C,
    int M, int N, int K) {
  __shared__ unsigned short As[BM * BK];
  __shared__ unsigned short Bs[BN * BK];
  const int tid  = threadIdx.x;
  const int lane = tid & 63;
  const int wid  = tid >> 6;
  const int wm   = wid >> 1;
  const int wn   = wid & 1;
  const int l16  = lane & 15;
  const int quad = lane >> 4;
  const int rowBase = blockIdx.y * BM;
  const int colBase = blockIdx.x * BN;

  f32x4 acc[4][4] = {};

  for (int k0 = 0; k0 < K; k0 += BK) {
#pragma unroll
    for (int it = 0; it < 4; ++it) {
      int cb = it * 256 + wid * 64;
      int c  = cb + lane;
      int row = c >> 3;
      int kk  = (c & 7) << 3;
      const unsigned short* ga = A + (size_t)(rowBase + row) * K + (k0 + kk);
      __builtin_amdgcn_global_load_lds(
          (const __attribute__((address_space(1))) void*)ga,
          (__attribute__((address_space(3))) void*)(As + (size_t)cb * 8), 16, 0, 0);
      const unsigned short* gb = Bm + (size_t)(colBase + row) * K + (k0 + kk);
      __builtin_amdgcn_global_load_lds(
          (const __attribute__((address_space(1))) void*)gb,
          (__attribute__((address_space(3))) void*)(Bs + (size_t)cb * 8), 16, 0, 0);
    }
    __syncthreads();
#pragma unroll
    for (int kk = 0; kk < BK; kk += 32) {
      bf16x8 af[4], bfr[4];
#pragma unroll
      for (int mt = 0; mt < 4; ++mt)
        af[mt] = *(const bf16x8*)(As + (wm * 64 + mt * 16 + l16) * BK + kk + quad * 8);
#pragma unroll
      for (int nt = 0; nt < 4; ++nt)
        bfr[nt] = *(const bf16x8*)(Bs + (wn * 64 + nt * 16 + l16) * BK + kk + quad * 8);
#pragma unroll
      for (int mt = 0; mt < 4; ++mt)
#pragma unroll
        for (int nt = 0; nt < 4; ++nt)
          acc[mt][nt] = __builtin_amdgcn_mfma_f32_16x16x32_bf16(af[mt], bfr[nt], acc[mt][nt], 0, 0, 0);
    }
    __syncthreads();
  }

  float bvals[4];
#pragma unroll
  for (int nt = 0; nt < 4; ++nt) bvals[nt] = bias[colBase + wn * 64 + nt * 16 + l16];
#pragma unroll
  for (int mt = 0; mt < 4; ++mt) {
#pragma unroll
    for (int r = 0; r < 4; ++r) {
      int row = rowBase + wm * 64 + mt * 16 + quad * 4 + r;
      unsigned short* cp = C + (size_t)row * N + colBase + wn * 64 + l16;
#pragma unroll
      for (int nt = 0; nt < 4; ++nt) {
        float v = fmaxf(acc[mt][nt][r] + bvals[nt], 0.0f);
        cp[nt * 16] = f2b(v);
      }
    }
  }
}

// ---------------- K3: GEMM3 (512->4) + per-scene routed 2x2 affines ----------------
__global__ __launch_bounds__(256) void head_kernel(
    const unsigned short* __restrict__ h2,  // [B,512] bf16
    const float* __restrict__ W3,           // [4,512]
    const float* __restrict__ b3,           // [4]
    const int* __restrict__ sidx,           // [B] int32
    const float* __restrict__ xyW,          // [72,2,2]
    const float* __restrict__ xyb,          // [72,2]
    const float* __restrict__ tW,           // [72,2,2]
    float* __restrict__ out) {              // [B,4]
  int wave = (blockIdx.x * blockDim.x + threadIdx.x) >> 6;
  int lane = threadIdx.x & 63;
  if (wave >= BROWS) return;

  bf16x8 hv = *(const bf16x8*)(h2 + (size_t)wave * 512 + lane * 8);
  float hf[8];
#pragma unroll
  for (int j = 0; j < 8; ++j) hf[j] = (float)hv[j];

  float s[4];
#pragma unroll
  for (int o = 0; o < 4; ++o) {
    const float* wrow = W3 + o * 512 + lane * 8;
    float4 w0 = ((const float4*)wrow)[0];
    float4 w1 = ((const float4*)wrow)[1];
    float a = hf[0] * w0.x + hf[1] * w0.y + hf[2] * w0.z + hf[3] * w0.w +
              hf[4] * w1.x + hf[5] * w1.y + hf[6] * w1.z + hf[7] * w1.w;
#pragma unroll
    for (int off = 32; off > 0; off >>= 1) a += __shfl_down(a, off, 64);
    s[o] = a;
  }

  if (lane == 0) {
#pragma unroll
    for (int o = 0; o < 4; ++o) s[o] += b3[o];
    int sc = sidx[wave];
    const float* wx = xyW + sc * 4;
    const float* bx = xyb + sc * 2;
    const float* wt = tW + sc * 4;
    float o0 = wx[0] * s[0] + wx[1] * s[1] + bx[0];
    float o1 = wx[2] * s[0] + wx[3] * s[1] + bx[1];
    float o2 = wt[0] * s[2] + wt[1] * s[3];
    float o3 = wt[2] * s[2] + wt[3] * s[3];
    ((float4*)out)[wave] = make_float4(o0, o1, o2, o3);
  }
}

// ---------------- workspace layout (bytes) ----------------
#define WS_W1B   0UL                      // 512*7680*2  = 7864320
#define WS_W2B   7864320UL                // + 512*512*2 = 524288
#define WS_H1    8388608UL                // + 8192*512*2
#define WS_H2    16777216UL               // + 8192*512*2
#define WS_PART  25165824UL               // + 4*8192*512*4 = 67108864
#define WS_NEED  92274688UL

extern "C" void kernel_launch(void* const* d_in, const int* in_sizes, int n_in,
                              void* d_out, int out_size, void* d_ws, size_t ws_size,
                              hipStream_t stream) {
  const float* feat = (const float*)d_in[0];
  const int*   sidx = (const int*)d_in[1];
  const float* W1   = (const float*)d_in[2];
  const float* b1   = (const float*)d_in[3];
  const float* W2   = (const float*)d_in[4];
  const float* b2   = (const float*)d_in[5];
  const float* W3   = (const float*)d_in[6];
  const float* b3   = (const float*)d_in[7];
  const float* xyW  = (const float*)d_in[8];
  const float* xyb  = (const float*)d_in[9];
  const float* tW   = (const float*)d_in[10];
  float* out = (float*)d_out;

  if (ws_size < WS_NEED) return;

  char* ws = (char*)d_ws;
  unsigned short* W1B  = (unsigned short*)(ws + WS_W1B);
  unsigned short* W2B  = (unsigned short*)(ws + WS_W2B);
  unsigned short* h1   = (unsigned short*)(ws + WS_H1);
  unsigned short* h2   = (unsigned short*)(ws + WS_H2);
  float*          part = (float*)(ws + WS_PART);

  // K0: convert weights fp32 -> bf16 (feat stays fp32, converted in-GEMM)
  cvt_kernel<<<512, 256, 0, stream>>>(W1, W1B, (HIDN * FEATK) / 4);
  cvt_kernel<<<64, 256, 0, stream>>>(W2, W2B, (HIDN * HIDN) / 4);

  // K1: partials = feat @ W1^T (split-K S=4, fused fp32->bf16 on A, reg-pipelined)
  gemm1_fused_splitk<<<dim3(4, BROWS / K1_BM), 256, 0, stream>>>(
      feat, W1B, part, BROWS, HIDN, FEATK, FEATK / 4);
  reduce4_bias_relu<<<(BROWS * HIDN / 4 + 255) / 256, 256, 0, stream>>>(
      part, b1, h1, BROWS * HIDN / 4, HIDN / 4);

  // K2: h2 = relu(h1 @ W2^T + b2)
  gemm_bt_bias_relu<<<dim3(HIDN / BN, BROWS / BM), 256, 0, stream>>>(
      h1, W2B, b2, h2, BROWS, HIDN, HIDN);

  // K3: shared = h2 @ W3^T + b3 ; routed 2x2 affines -> out
  head_kernel<<<(BROWS * 64) / 256, 256, 0, stream>>>(
      h2, W3, b3, sidx, xyW, xyb, tW, out);
}